// Round 9
// baseline (116.789 us; speedup 1.0000x reference)
//
#include <hip/hip_runtime.h>
#include <hip/hip_bf16.h>
#include <math.h>

typedef __bf16 bf16x8 __attribute__((ext_vector_type(8)));
typedef float f32x4 __attribute__((ext_vector_type(4)));
typedef unsigned short u16x8 __attribute__((ext_vector_type(8)));
typedef _Float16 h16x4 __attribute__((ext_vector_type(4)));
typedef unsigned short u16;

#define S_LEN 2048
#define DMODEL 1024
#define NH 16
#define NROWS 65536   // 2*16*2048 (b,h,s) rows

__device__ __forceinline__ u16 f2bf(float f) {
    __bf16 b = (__bf16)f;
    return __builtin_bit_cast(u16, b);
}
__device__ __forceinline__ float bf2f(u16 u) {
    union { unsigned int i; float f; } v; v.i = ((unsigned int)u) << 16; return v.f;
}

// global -> LDS direct copy, 16B per lane (wave-uniform LDS base + lane*16).
__device__ __forceinline__ void gload16(const u16* g, u16* lds_base) {
    __builtin_amdgcn_global_load_lds(
        (const __attribute__((address_space(1))) unsigned int*)g,
        (__attribute__((address_space(3))) unsigned int*)lds_base,
        16, 0, 0);
}

// ---------- X f32 -> bf16 ----------
__global__ __launch_bounds__(256) void cvt_x(const float* __restrict__ in, u16* __restrict__ outp) {
    int i = (blockIdx.x * 256 + threadIdx.x) * 4;
    float4 v = *(const float4*)(in + i);
    outp[i + 0] = f2bf(v.x); outp[i + 1] = f2bf(v.y);
    outp[i + 2] = f2bf(v.z); outp[i + 3] = f2bf(v.w);
}

// ---------- W [1024][3072] f32 -> Wt [3072][1024] bf16 ----------
__global__ __launch_bounds__(256) void transpose_w(const float* __restrict__ W, u16* __restrict__ Wt) {
    __shared__ u16 tile[32][33];
    int n0 = blockIdx.x * 32, k0 = blockIdx.y * 32;
    int tx = threadIdx.x & 31, ty = threadIdx.x >> 5;
#pragma unroll
    for (int i = 0; i < 4; i++) {
        int k = ty + i * 8;
        tile[k][tx] = f2bf(W[(size_t)(k0 + k) * 3072 + n0 + tx]);
    }
    __syncthreads();
#pragma unroll
    for (int i = 0; i < 4; i++) {
        int n = ty + i * 8;
        Wt[(size_t)(n0 + n) * 1024 + k0 + tx] = tile[tx][n];
    }
}

// ---------- QKV GEMM (unchanged, ~860 TF) ----------
__global__ __launch_bounds__(256) void qkv_gemm(const u16* __restrict__ A, const u16* __restrict__ Bt,
                                                u16* __restrict__ C) {
    __shared__ alignas(16) u16 As[128 * 64];
    __shared__ alignas(16) u16 Bs[128 * 64];
    const int tid = threadIdx.x, l = tid & 63, w = tid >> 6;
    const int bm = blockIdx.y, bn = blockIdx.x;
    const int wm = w >> 1, wn = w & 1;
    const int c0 = l & 15, g = l >> 4;
    f32x4 acc[4][4] = {};
    for (int kt = 0; kt < 1024; kt += 64) {
        __syncthreads();
#pragma unroll
        for (int n = 0; n < 4; n++) {
            int i = tid + n * 256;
            int r = i >> 3, c = i & 7;
            int cs = c ^ (r & 7);
            u16* dstA = As + (size_t)(w * 64 + n * 256) * 8;
            u16* dstB = Bs + (size_t)(w * 64 + n * 256) * 8;
            gload16(A + (size_t)(bm * 128 + r) * 1024 + kt + cs * 8, dstA);
            gload16(Bt + (size_t)(bn * 128 + r) * 1024 + kt + cs * 8, dstB);
        }
        __syncthreads();
#pragma unroll
        for (int kk = 0; kk < 2; kk++) {
            bf16x8 af[4], bfr[4];
#pragma unroll
            for (int m = 0; m < 4; m++) {
                int row = wm * 64 + m * 16 + c0;
                af[m] = *(const bf16x8*)((const char*)As + row * 128 + (((g + kk * 4) ^ (row & 7)) << 4));
            }
#pragma unroll
            for (int n = 0; n < 4; n++) {
                int row = wn * 64 + n * 16 + c0;
                bfr[n] = *(const bf16x8*)((const char*)Bs + row * 128 + (((g + kk * 4) ^ (row & 7)) << 4));
            }
#pragma unroll
            for (int m = 0; m < 4; m++)
#pragma unroll
                for (int n = 0; n < 4; n++)
                    acc[m][n] = __builtin_amdgcn_mfma_f32_16x16x32_bf16(af[m], bfr[n], acc[m][n], 0, 0, 0);
        }
    }
#pragma unroll
    for (int m = 0; m < 4; m++)
#pragma unroll
        for (int n = 0; n < 4; n++)
#pragma unroll
            for (int j = 0; j < 4; j++) {
                int row = bm * 128 + wm * 64 + m * 16 + 4 * g + j;
                int col = bn * 128 + wn * 64 + n * 16 + c0;
                C[(size_t)row * 3072 + col] = f2bf(acc[m][n][j]);
            }
}

// ---------- V -> permuted V^T: Vtp[bh][d][spos], spos = (s&~63) | perm(s&63) ----------
// perm(t): kb=t>>4, g=(t>>2)&3, j=t&3 -> pos = 32*(kb>>1) + 8*g + 4*(kb&1) + j  (R2-R7 verified)
__global__ __launch_bounds__(256) void transpose_v(const u16* __restrict__ QKV, u16* __restrict__ Vtp) {
    __shared__ u16 tile[64][72];
    const int bh = blockIdx.x >> 5, st = blockIdx.x & 31;
    const int b = bh >> 4, h = bh & 15;
    const u16* src = QKV + (size_t)b * S_LEN * 3072 + 2048 + h * 64;
    const int sl = threadIdx.x >> 2;
    const int cg = (threadIdx.x & 3) * 16;
#pragma unroll
    for (int ii = 0; ii < 2; ii++) {
        u16x8 v = *(const u16x8*)(src + (size_t)(st * 64 + sl) * 3072 + cg + ii * 8);
        *(u16x8*)&tile[sl][cg + ii * 8] = v;
    }
    __syncthreads();
    const int dl = threadIdx.x >> 2;
#pragma unroll
    for (int ii = 0; ii < 2; ii++) {
        u16x8 o;
#pragma unroll
        for (int q = 0; q < 8; q++) {
            int p = cg + ii * 8 + q;
            int kb = 2 * (p >> 5) + ((p >> 2) & 1);
            int t = kb * 16 + ((p >> 3) & 3) * 4 + (p & 3);
            o[q] = tile[t][dl];
        }
        *(u16x8*)(Vtp + ((size_t)bh * 64 + dl) * S_LEN + st * 64 + cg + ii * 8) = o;
    }
}

// ---------- Flash attention v9: attn4 wave shape (4 waves x 16q, 16x16 MFMA) +
// across-wave KV-split x2 (16 tiles/wave) + baked -m_r acc init (no subs) +
// lane-local defer check (no shfls common path) + ones-MFMA l. ----------
__global__ __launch_bounds__(256, 4) void attn9(const u16* __restrict__ QKV, const u16* __restrict__ Vtp,
                                                float* __restrict__ outp, _Float16* __restrict__ Op1,
                                                float* __restrict__ Mp, float* __restrict__ Lp) {
    __shared__ alignas(16) u16 Ks[2][64 * 64];   // [key][d-chunk], chunk^=(key&7)
    __shared__ alignas(16) u16 Vs[2][64 * 64];   // [d][pos-chunk], chunk^=(d&7)
    const int bid = blockIdx.x;
    const int wg = ((bid & 7) << 8) | (bid >> 3);   // 2048 = 8*256, bijective XCD swizzle
    const int tid = threadIdx.x, l = tid & 63, w = tid >> 6;
    const int bh = wg >> 6, rest = wg & 63;
    const int qt = rest >> 1, hf = rest & 1;        // qt in [0,32), hf = KV half
    const int b = bh >> 4, h = bh & 15;
    const int c0 = l & 15, g = l >> 4;
    const u16* Qb = QKV + (size_t)b * S_LEN * 3072 + h * 64;
    const u16* Kb = Qb + 1024;
    const u16* Vb = Vtp + (size_t)bh * 64 * S_LEN;
    const int kv0 = hf * 1024;
    const int qrow = qt * 64 + w * 16 + c0;

    // staging: chunks {tid, tid+256}, pre-swizzled source col
    const int r0 = tid >> 3, cs0 = (tid & 7) ^ (r0 & 7);
    const int i1 = tid + 256, r1 = i1 >> 3, cs1 = (i1 & 7) ^ (r1 & 7);
    const int dbA = (w * 64) * 8, dbB = (256 + w * 64) * 8;

    // unified LDS read offsets: off[x*2+kk] serves K (x=kb) and V (x=n) since key&7==d&7==c0&7
    int off[8];
#pragma unroll
    for (int x = 0; x < 4; x++)
#pragma unroll
        for (int kk = 0; kk < 2; kk++)
            off[x * 2 + kk] = (x * 16 + c0) * 128 + (((g + 4 * kk) ^ (c0 & 7)) << 4);

    // Q B-frags; fold (1/8)*log2(e)
    bf16x8 qf[2];
    {
        const float qs = 0.125f * 1.44269504f;
#pragma unroll
        for (int kk = 0; kk < 2; kk++) {
            u16x8 v = *(const u16x8*)(Qb + (size_t)qrow * 3072 + kk * 32 + g * 8);
            bf16x8 q;
#pragma unroll
            for (int j = 0; j < 8; j++) q[j] = (__bf16)(bf2f(v[j]) * qs);
            qf[kk] = q;
        }
    }
    bf16x8 vone;
#pragma unroll
    for (int j = 0; j < 8; j++) vone[j] = (__bf16)1.0f;

    float m_r = 0.f;             // baked-init scheme: scores are accumulated as S - m_r
    f32x4 accO[4] = {};
    f32x4 accL = {};

    // prologue: stage tile kv0 into buf 0
    gload16(Kb + (size_t)(kv0 + r0) * 3072 + cs0 * 8, Ks[0] + dbA);
    gload16(Kb + (size_t)(kv0 + r1) * 3072 + cs1 * 8, Ks[0] + dbB);
    gload16(Vb + (size_t)r0 * S_LEN + kv0 + cs0 * 8, Vs[0] + dbA);
    gload16(Vb + (size_t)r1 * S_LEN + kv0 + cs1 * 8, Vs[0] + dbB);

    for (int t = 0; t < 16; t++) {
        const int cur = t & 1;
        __syncthreads();  // buf[cur] staged (vmcnt drained at barrier) + prev reads done
        if (t + 1 < 16) {
            const int kvn = kv0 + (t + 1) * 64;
            gload16(Kb + (size_t)(kvn + r0) * 3072 + cs0 * 8, Ks[cur ^ 1] + dbA);
            gload16(Kb + (size_t)(kvn + r1) * 3072 + cs1 * 8, Ks[cur ^ 1] + dbB);
            gload16(Vb + (size_t)r0 * S_LEN + kvn + cs0 * 8, Vs[cur ^ 1] + dbA);
            gload16(Vb + (size_t)r1 * S_LEN + kvn + cs1 * 8, Vs[cur ^ 1] + dbB);
        }
        const char* Kc = (const char*)Ks[cur];
        const char* Vc = (const char*)Vs[cur];
        // QK^T (swapped) with C-in = -m_r: sc = S - m_r directly (kills the pre-exp2 subs)
        f32x4 sc[4];
        const float nm = -m_r;
#pragma unroll
        for (int kb = 0; kb < 4; kb++) { sc[kb][0] = nm; sc[kb][1] = nm; sc[kb][2] = nm; sc[kb][3] = nm; }
        __builtin_amdgcn_s_setprio(1);
#pragma unroll
        for (int kb = 0; kb < 4; kb++)
#pragma unroll
            for (int kk = 0; kk < 2; kk++) {
                bf16x8 kf = *(const bf16x8*)(Kc + off[kb * 2 + kk]);
                sc[kb] = __builtin_amdgcn_mfma_f32_16x16x32_bf16(kf, qf[kk], sc[kb], 0, 0, 0);
            }
        __builtin_amdgcn_s_setprio(0);
        // V fragment reads (latency hides under softmax)
        bf16x8 vf[2][4];
#pragma unroll
        for (int kk = 0; kk < 2; kk++)
#pragma unroll
            for (int n = 0; n < 4; n++)
                vf[kk][n] = *(const bf16x8*)(Vc + off[n * 2 + kk]);
        // lane-local max of baked scores (no cross-lane shfl in the common path)
        float m0 = fmaxf(fmaxf(sc[0][0], sc[0][1]), sc[0][2]);
        float m1 = fmaxf(fmaxf(sc[0][3], sc[1][0]), sc[1][1]);
        float m2 = fmaxf(fmaxf(sc[1][2], sc[1][3]), sc[2][0]);
        float m3 = fmaxf(fmaxf(sc[2][1], sc[2][2]), sc[2][3]);
        float m4 = fmaxf(fmaxf(sc[3][0], sc[3][1]), sc[3][2]);
        float mx = fmaxf(fmaxf(fmaxf(m0, m1), m2), fmaxf(fmaxf(m3, m4), sc[3][3]));
        // defer-max: rescale only if some lane's local growth exceeds 8 (log2 domain)
        if (!__all(mx <= 8.f)) {
            float mxr = fmaxf(mx, __shfl_xor(mx, 16));
            mxr = fmaxf(mxr, __shfl_xor(mxr, 32));        // per-q full-row baked max
            float adj = fmaxf(mxr, 0.f);                  // shift amount for q=c0
            float alpha = __builtin_amdgcn_exp2f(-adj);
            m_r += adj;
#pragma unroll
            for (int j = 0; j < 4; j++) {
                float aj = __shfl(alpha, 20 * g + j);
                accL[j] *= aj;
#pragma unroll
                for (int n = 0; n < 4; n++) accO[n][j] *= aj;
            }
#pragma unroll
            for (int kb = 0; kb < 4; kb++)
#pragma unroll
                for (int j = 0; j < 4; j++) sc[kb][j] -= adj;
        }
        // P = exp2(baked scores)
#pragma unroll
        for (int kb = 0; kb < 4; kb++)
#pragma unroll
            for (int j = 0; j < 4; j++)
                sc[kb][j] = __builtin_amdgcn_exp2f(sc[kb][j]);
        // PV + l (accL = P @ ones, rows match accO)
        __builtin_amdgcn_s_setprio(1);
#pragma unroll
        for (int kk = 0; kk < 2; kk++) {
            bf16x8 pf;
#pragma unroll
            for (int j = 0; j < 4; j++) {
                pf[j]     = (__bf16)sc[2 * kk][j];
                pf[j + 4] = (__bf16)sc[2 * kk + 1][j];
            }
            accL = __builtin_amdgcn_mfma_f32_16x16x32_bf16(pf, vone, accL, 0, 0, 0);
#pragma unroll
            for (int n = 0; n < 4; n++)
                accO[n] = __builtin_amdgcn_mfma_f32_16x16x32_bf16(pf, vf[kk][n], accO[n], 0, 0, 0);
        }
        __builtin_amdgcn_s_setprio(0);
    }
    // epilogue: half 0 -> normalized f32 to out; half 1 -> normalized fp16 partial; (m,l) stored
    const int rowbase = qt * 64 + w * 16;
    const int rowg0 = bh * 2048 + rowbase;
    if (hf == 0) {
#pragma unroll
        for (int j = 0; j < 4; j++) {
            float inv = 1.0f / accL[j];
            int row = rowbase + 4 * g + j;
            float* op = outp + ((size_t)b * S_LEN + row) * DMODEL + h * 64;
#pragma unroll
            for (int n = 0; n < 4; n++) op[n * 16 + c0] = accO[n][j] * inv;
        }
    } else {
#pragma unroll
        for (int j = 0; j < 4; j++) {
            float inv = 1.0f / accL[j];
            size_t rg = (size_t)(rowg0 + 4 * g + j) * 64;
#pragma unroll
            for (int n = 0; n < 4; n++) Op1[rg + n * 16 + c0] = (_Float16)(accO[n][j] * inv);
        }
    }
    if (g == 0) Mp[hf * NROWS + rowg0 + c0] = m_r;
    if (c0 == 0) {
#pragma unroll
        for (int j = 0; j < 4; j++) Lp[hf * NROWS + rowg0 + 4 * g + j] = accL[j];
    }
}

// ---------- merge: out = w0*O0 + w1*O1, w_i = 2^(m_i-M) * l_i / sum ----------
__global__ __launch_bounds__(256) void attn_merge(float* __restrict__ outp, const _Float16* __restrict__ Op1,
                                                  const float* __restrict__ Mp, const float* __restrict__ Lp) {
    int t = blockIdx.x * 256 + threadIdx.x;   // 262144 threads: 4 per row
    int r = t >> 2;
    int dc = (t & 3) * 16;
    int bh = r >> 11, srow = r & 2047;
    int b = bh >> 4, h = bh & 15;
    float m0 = Mp[r], m1 = Mp[NROWS + r];
    float l0 = Lp[r], l1 = Lp[NROWS + r];
    float M = fmaxf(m0, m1);
    float w0 = __builtin_amdgcn_exp2f(m0 - M) * l0;
    float w1 = __builtin_amdgcn_exp2f(m1 - M) * l1;
    float inv = 1.0f / (w0 + w1);
    float a0 = w0 * inv, a1 = w1 * inv;
    float* op = outp + ((size_t)b * S_LEN + srow) * DMODEL + h * 64 + dc;
    const _Float16* o1 = Op1 + (size_t)r * 64 + dc;
#pragma unroll
    for (int q = 0; q < 4; q++) {
        float4 v0 = *(const float4*)(op + q * 4);
        h16x4 v1 = *(const h16x4*)(o1 + q * 4);
        v0.x = a0 * v0.x + a1 * (float)v1[0];
        v0.y = a0 * v0.y + a1 * (float)v1[1];
        v0.z = a0 * v0.z + a1 * (float)v1[2];
        v0.w = a0 * v0.w + a1 * (float)v1[3];
        *(float4*)(op + q * 4) = v0;
    }
}

extern "C" void kernel_launch(void* const* d_in, const int* in_sizes, int n_in,
                              void* d_out, int out_size, void* d_ws, size_t ws_size,
                              hipStream_t stream) {
    const float* X = (const float*)d_in[0];
    const float* W = (const float*)d_in[1];
    float* out = (float*)d_out;

    u16* Xb  = (u16*)d_ws;                        // 4096*1024 bf16 — dead after gemm
    u16* Wt  = Xb + (size_t)4096 * 1024;          // 3072*1024 bf16 — dead after gemm
    u16* QKV = Wt + (size_t)3072 * 1024;          // 4096*3072 bf16
    u16* Vtp = QKV + (size_t)4096 * 3072;         // 32*64*2048 bf16 (~48MB total)
    _Float16* Op1 = (_Float16*)Xb;                // 65536*64 fp16 = 8.4MB (== Xb size)
    float* Mp = (float*)Wt;                       // 2*65536 f32
    float* Lp = Mp + 2 * NROWS;                   // 2*65536 f32 (fits in Wt)

    cvt_x<<<4096, 256, 0, stream>>>(X, Xb);
    transpose_w<<<dim3(96, 32), 256, 0, stream>>>(W, Wt);
    qkv_gemm<<<dim3(24, 32), 256, 0, stream>>>(Xb, Wt, QKV);
    transpose_v<<<1024, 256, 0, stream>>>(QKV, Vtp);
    attn9<<<2048, 256, 0, stream>>>(QKV, Vtp, out, Op1, Mp, Lp);
    attn_merge<<<1024, 256, 0, stream>>>(out, Op1, Mp, Lp);
}